// Round 1
// baseline (1105.972 us; speedup 1.0000x reference)
//
#include <hip/hip_runtime.h>

// GCN 3-layer + mean pool, MI355X.
// Pipeline per call:
//   1. histogram in-degree (counts) over dst          [int atomics]
//   2. dis = rsqrt(counts+1)
//   3. exclusive scan counts -> row_start (2-level)
//   4. scatter edges into dst-CSR (col = src)
//   5. GEMM(x,W1)->bufA; AGG+relu -> bufB
//   6. GEMM(bufB,W2)->bufA; AGG+relu -> bufB
//   7. GEMM(bufB,W3)->bufA; AGG -> d_out features
//   8. pool (atomics) -> finalize avg into d_out tail
//
// GEMM: W (<=64KB) fully staged in LDS, one thread per (row,col),
// wave-uniform float4 x loads, 4 independent FMA chains for ILP.
// AGG: one wave per node over its CSR row; register accumulate; no atomics.

constexpr int KDIM = 128;   // inner dim of all three GEMMs
constexpr int NGRAPH = 64;

__global__ void k_init(int* __restrict__ counts, float* __restrict__ pool,
                       int n, int poolN) {
  int i = blockIdx.x * blockDim.x + threadIdx.x;
  int stride = gridDim.x * blockDim.x;
  for (int j = i; j < n; j += stride) counts[j] = 0;
  for (int j = i; j < poolN; j += stride) pool[j] = 0.f;
}

__global__ void k_hist(const int* __restrict__ src, const int* __restrict__ dst,
                       int* __restrict__ counts, int e, int n) {
  int i = blockIdx.x * blockDim.x + threadIdx.x;
  int stride = gridDim.x * blockDim.x;
  for (int j = i; j < e; j += stride) {
    int s = src[j], d = dst[j];
    if ((unsigned)s < (unsigned)n && (unsigned)d < (unsigned)n)
      atomicAdd(&counts[d], 1);
  }
}

__global__ void k_dis(const int* __restrict__ counts, float* __restrict__ dis, int n) {
  int i = blockIdx.x * blockDim.x + threadIdx.x;
  int stride = gridDim.x * blockDim.x;
  for (int j = i; j < n; j += stride)
    dis[j] = rsqrtf((float)counts[j] + 1.0f);
}

// per-block exclusive scan; blockSums[b] = block total
__global__ void k_scan_block(const int* __restrict__ in, int* __restrict__ outExcl,
                             int* __restrict__ blockSums, int n) {
  __shared__ int s[256];
  int tid = threadIdx.x;
  int i = blockIdx.x * 256 + tid;
  int v = (i < n) ? in[i] : 0;
  int x = v;
  s[tid] = x;
  __syncthreads();
  for (int off = 1; off < 256; off <<= 1) {
    int t = (tid >= off) ? s[tid - off] : 0;
    __syncthreads();
    x += t;
    s[tid] = x;
    __syncthreads();
  }
  if (i < n) outExcl[i] = x - v;
  if (tid == 255) blockSums[blockIdx.x] = x;
}

// single block: in-place exclusive scan of blockSums[0..nb); total -> blockSums[256]
__global__ void k_scan_offsets(int* __restrict__ bs, int nb) {
  __shared__ int s[256];
  int tid = threadIdx.x;
  int v = (tid < nb) ? bs[tid] : 0;
  int x = v;
  s[tid] = x;
  __syncthreads();
  for (int off = 1; off < 256; off <<= 1) {
    int t = (tid >= off) ? s[tid - off] : 0;
    __syncthreads();
    x += t;
    s[tid] = x;
    __syncthreads();
  }
  if (tid < nb) bs[tid] = x - v;
  if (tid == nb - 1) bs[256] = x;  // total valid edges
}

__global__ void k_scan_add(int* __restrict__ row_start, const int* __restrict__ bs,
                           int* __restrict__ cursor, int n) {
  int i = blockIdx.x * blockDim.x + threadIdx.x;
  int stride = gridDim.x * blockDim.x;
  for (int j = i; j < n; j += stride) {
    int r = row_start[j] + bs[j >> 8];
    row_start[j] = r;
    cursor[j] = r;
  }
  if (i == 0) row_start[n] = bs[256];
}

__global__ void k_scatter(const int* __restrict__ src, const int* __restrict__ dst,
                          int* __restrict__ cursor, int* __restrict__ colA,
                          int e, int n) {
  int i = blockIdx.x * blockDim.x + threadIdx.x;
  int stride = gridDim.x * blockDim.x;
  for (int j = i; j < e; j += stride) {
    int s = src[j], d = dst[j];
    if ((unsigned)s < (unsigned)n && (unsigned)d < (unsigned)n) {
      int pos = atomicAdd(&cursor[d], 1);
      colA[pos] = s;
    }
  }
}

// H[row][col] = sum_k X[row][k] * W[k][col], K=128 fixed, W staged in LDS.
template <int DOUT_T>
__global__ __launch_bounds__(256) void k_gemm(const float* __restrict__ X,
                                              const float* __restrict__ W,
                                              float* __restrict__ H, int n,
                                              int rowsPerBlock) {
  __shared__ float Wl[KDIM * DOUT_T];
  for (int i = threadIdx.x; i < KDIM * DOUT_T; i += 256) Wl[i] = W[i];
  __syncthreads();

  const int col = threadIdx.x % DOUT_T;
  const int sub = threadIdx.x / DOUT_T;  // which row of the concurrent set
  constexpr int RPI = 256 / DOUT_T;      // rows processed per iteration
  const int row0 = blockIdx.x * rowsPerBlock;

  for (int r = sub; r < rowsPerBlock; r += RPI) {
    const int row = row0 + r;
    if (row >= n) break;
    const float4* xr = reinterpret_cast<const float4*>(X + (size_t)row * KDIM);
    float a0 = 0.f, a1 = 0.f, a2 = 0.f, a3 = 0.f;
#pragma unroll
    for (int k4 = 0; k4 < KDIM / 4; ++k4) {
      float4 xv = xr[k4];
      a0 = fmaf(xv.x, Wl[(k4 * 4 + 0) * DOUT_T + col], a0);
      a1 = fmaf(xv.y, Wl[(k4 * 4 + 1) * DOUT_T + col], a1);
      a2 = fmaf(xv.z, Wl[(k4 * 4 + 2) * DOUT_T + col], a2);
      a3 = fmaf(xv.w, Wl[(k4 * 4 + 3) * DOUT_T + col], a3);
    }
    H[(size_t)row * DOUT_T + col] = (a0 + a1) + (a2 + a3);
  }
}

// One wave per node: OUT[i] = sum_{e: dst=i} H[src[e]] * dis[src]*dis[i]
//                           + H[i]*dis[i]^2 + bias   (optional relu)
template <int D, bool RELU>
__global__ __launch_bounds__(256) void k_agg(const float* __restrict__ H,
                                             const int* __restrict__ row_start,
                                             const int* __restrict__ colA,
                                             const float* __restrict__ dis,
                                             const float* __restrict__ bias,
                                             float* __restrict__ OUT, int n) {
  const int wave = threadIdx.x >> 6;
  const int lane = threadIdx.x & 63;
  const int node = blockIdx.x * 4 + wave;
  if (node >= n) return;
  constexpr int C = D / 64;
  float acc[C];
#pragma unroll
  for (int c = 0; c < C; ++c) acc[c] = 0.f;

  const int beg = row_start[node];
  const int end = row_start[node + 1];
  const float di = dis[node];
  for (int e = beg; e < end; ++e) {
    const int s = colA[e];
    const float nrm = dis[s] * di;
    const float* hs = H + (size_t)s * D;
#pragma unroll
    for (int c = 0; c < C; ++c) acc[c] = fmaf(hs[lane + 64 * c], nrm, acc[c]);
  }
  const float* hn = H + (size_t)node * D;
  const float di2 = di * di;
  float* o = OUT + (size_t)node * D;
#pragma unroll
  for (int c = 0; c < C; ++c) {
    float v = acc[c] + hn[lane + 64 * c] * di2 + bias[lane + 64 * c];
    if (RELU) v = fmaxf(v, 0.f);
    o[lane + 64 * c] = v;
  }
}

__global__ void k_pool(const float* __restrict__ F, const int* __restrict__ batch,
                       float* __restrict__ sums, float* __restrict__ cnt, int n) {
  const int wave = threadIdx.x >> 6;
  const int lane = threadIdx.x & 63;
  const int stride = gridDim.x * 4;
  for (int node = blockIdx.x * 4 + wave; node < n; node += stride) {
    const int g = batch[node];
    if ((unsigned)g < (unsigned)NGRAPH) {
      atomicAdd(&sums[g * 64 + lane], F[(size_t)node * 64 + lane]);
      if (lane == 0) atomicAdd(&cnt[g], 1.f);
    }
  }
}

__global__ void k_final(const float* __restrict__ sums, const float* __restrict__ cnt,
                        float* __restrict__ out) {
  int i = blockIdx.x * blockDim.x + threadIdx.x;
  if (i < NGRAPH * 64) {
    int g = i >> 6;
    out[i] = sums[i] / fmaxf(cnt[g], 1.f);
  }
}

extern "C" void kernel_launch(void* const* d_in, const int* in_sizes, int n_in,
                              void* d_out, int out_size, void* d_ws, size_t ws_size,
                              hipStream_t stream) {
  const float* x     = (const float*)d_in[0];
  const int*   ei    = (const int*)d_in[1];
  const int*   batch = (const int*)d_in[2];
  const float* W1 = (const float*)d_in[3];
  const float* b1 = (const float*)d_in[4];
  const float* W2 = (const float*)d_in[5];
  const float* b2 = (const float*)d_in[6];
  const float* W3 = (const float*)d_in[7];
  const float* b3 = (const float*)d_in[8];

  const int n = in_sizes[0] / KDIM;   // 50000
  const int e = in_sizes[1] / 2;      // 800000
  const int* src = ei;
  const int* dst = ei + e;

  // workspace layout (256B-aligned slices)
  char* p = (char*)d_ws;
  size_t off = 0;
  auto carve = [&](size_t bytes) {
    char* r = p + off;
    off = (off + bytes + 255) & ~(size_t)255;
    return r;
  };
  float* bufA      = (float*)carve((size_t)n * KDIM * 4);
  float* bufB      = (float*)carve((size_t)n * KDIM * 4);
  float* dis       = (float*)carve((size_t)n * 4);
  int*   counts    = (int*)carve((size_t)n * 4);
  int*   row_start = (int*)carve((size_t)(n + 1) * 4);
  int*   cursor    = (int*)carve((size_t)n * 4);
  int*   colA      = (int*)carve((size_t)e * 4);
  int*   blockSums = (int*)carve(512 * 4);
  float* pool      = (float*)carve((size_t)(NGRAPH * 64 + NGRAPH) * 4);
  (void)ws_size;

  const int nb1 = (n + 255) / 256;  // 196 (<=256 required for single-block scan2)
  const int GS = 1024;              // grid for grid-stride kernels

  k_init<<<GS, 256, 0, stream>>>(counts, pool, n, NGRAPH * 64 + NGRAPH);
  k_hist<<<GS, 256, 0, stream>>>(src, dst, counts, e, n);
  k_dis<<<nb1, 256, 0, stream>>>(counts, dis, n);
  k_scan_block<<<nb1, 256, 0, stream>>>(counts, row_start, blockSums, n);
  k_scan_offsets<<<1, 256, 0, stream>>>(blockSums, nb1);
  k_scan_add<<<nb1, 256, 0, stream>>>(row_start, blockSums, cursor, n);
  k_scatter<<<GS, 256, 0, stream>>>(src, dst, cursor, colA, e, n);

  const int gemmGrid = (n + 31) / 32;
  const int aggGrid  = (n + 3) / 4;

  // layer 1
  k_gemm<128><<<gemmGrid, 256, 0, stream>>>(x, W1, bufA, n, 32);
  k_agg<128, true><<<aggGrid, 256, 0, stream>>>(bufA, row_start, colA, dis, b1, bufB, n);
  // layer 2
  k_gemm<128><<<gemmGrid, 256, 0, stream>>>(bufB, W2, bufA, n, 32);
  k_agg<128, true><<<aggGrid, 256, 0, stream>>>(bufA, row_start, colA, dis, b2, bufB, n);
  // layer 3
  k_gemm<64><<<gemmGrid, 256, 0, stream>>>(bufB, W3, bufA, n, 32);
  k_agg<64, false><<<aggGrid, 256, 0, stream>>>(bufA, row_start, colA, dis, b3,
                                                (float*)d_out, n);
  // pooling
  k_pool<<<2048, 256, 0, stream>>>((const float*)d_out, batch, pool,
                                   pool + NGRAPH * 64, n);
  k_final<<<16, 256, 0, stream>>>(pool, pool + NGRAPH * 64,
                                  (float*)d_out + (size_t)n * 64);
}

// Round 2
// 763.613 us; speedup vs baseline: 1.4483x; 1.4483x over previous
//
#include <hip/hip_runtime.h>

// GCN 3-layer + mean pool, MI355X.
// Pipeline per call:
//   1. histogram in-degree (counts) over dst          [int atomics]
//   2. dis = rsqrt(counts+1)
//   3. exclusive scan counts -> row_start (2-level)
//   4. scatter edges into dst-CSR (col = src)
//   5. GEMM(x,W1)->bufA; AGG+relu -> bufB
//   6. GEMM(bufB,W2)->bufA; AGG+relu -> bufB
//   7. GEMM(bufB,W3)->bufA; AGG -> d_out features
//   8. pool: batch is SORTED -> per-graph segmented reduction, no atomics
//
// R1 post-mortem: k_pool (atomicAdd storm, 3.2M atomics / 4096 addrs) was
// 377us of 1106us at 0.23% VALUBusy. Replaced with binary-search segmented
// reduction (k_pool2), one block per graph, deterministic, atomic-free.

constexpr int KDIM = 128;   // inner dim of all three GEMMs
constexpr int NGRAPH = 64;

__global__ void k_init(int* __restrict__ counts, int n) {
  int i = blockIdx.x * blockDim.x + threadIdx.x;
  int stride = gridDim.x * blockDim.x;
  for (int j = i; j < n; j += stride) counts[j] = 0;
}

__global__ void k_hist(const int* __restrict__ src, const int* __restrict__ dst,
                       int* __restrict__ counts, int e, int n) {
  int i = blockIdx.x * blockDim.x + threadIdx.x;
  int stride = gridDim.x * blockDim.x;
  for (int j = i; j < e; j += stride) {
    int s = src[j], d = dst[j];
    if ((unsigned)s < (unsigned)n && (unsigned)d < (unsigned)n)
      atomicAdd(&counts[d], 1);
  }
}

__global__ void k_dis(const int* __restrict__ counts, float* __restrict__ dis, int n) {
  int i = blockIdx.x * blockDim.x + threadIdx.x;
  int stride = gridDim.x * blockDim.x;
  for (int j = i; j < n; j += stride)
    dis[j] = rsqrtf((float)counts[j] + 1.0f);
}

// per-block exclusive scan; blockSums[b] = block total
__global__ void k_scan_block(const int* __restrict__ in, int* __restrict__ outExcl,
                             int* __restrict__ blockSums, int n) {
  __shared__ int s[256];
  int tid = threadIdx.x;
  int i = blockIdx.x * 256 + tid;
  int v = (i < n) ? in[i] : 0;
  int x = v;
  s[tid] = x;
  __syncthreads();
  for (int off = 1; off < 256; off <<= 1) {
    int t = (tid >= off) ? s[tid - off] : 0;
    __syncthreads();
    x += t;
    s[tid] = x;
    __syncthreads();
  }
  if (i < n) outExcl[i] = x - v;
  if (tid == 255) blockSums[blockIdx.x] = x;
}

// single block: in-place exclusive scan of blockSums[0..nb); total -> blockSums[256]
__global__ void k_scan_offsets(int* __restrict__ bs, int nb) {
  __shared__ int s[256];
  int tid = threadIdx.x;
  int v = (tid < nb) ? bs[tid] : 0;
  int x = v;
  s[tid] = x;
  __syncthreads();
  for (int off = 1; off < 256; off <<= 1) {
    int t = (tid >= off) ? s[tid - off] : 0;
    __syncthreads();
    x += t;
    s[tid] = x;
    __syncthreads();
  }
  if (tid < nb) bs[tid] = x - v;
  if (tid == nb - 1) bs[256] = x;  // total valid edges
}

__global__ void k_scan_add(int* __restrict__ row_start, const int* __restrict__ bs,
                           int* __restrict__ cursor, int n) {
  int i = blockIdx.x * blockDim.x + threadIdx.x;
  int stride = gridDim.x * blockDim.x;
  for (int j = i; j < n; j += stride) {
    int r = row_start[j] + bs[j >> 8];
    row_start[j] = r;
    cursor[j] = r;
  }
  if (i == 0) row_start[n] = bs[256];
}

__global__ void k_scatter(const int* __restrict__ src, const int* __restrict__ dst,
                          int* __restrict__ cursor, int* __restrict__ colA,
                          int e, int n) {
  int i = blockIdx.x * blockDim.x + threadIdx.x;
  int stride = gridDim.x * blockDim.x;
  for (int j = i; j < e; j += stride) {
    int s = src[j], d = dst[j];
    if ((unsigned)s < (unsigned)n && (unsigned)d < (unsigned)n) {
      int pos = atomicAdd(&cursor[d], 1);
      colA[pos] = s;
    }
  }
}

// H[row][col] = sum_k X[row][k] * W[k][col], K=128 fixed, W staged in LDS.
template <int DOUT_T>
__global__ __launch_bounds__(256) void k_gemm(const float* __restrict__ X,
                                              const float* __restrict__ W,
                                              float* __restrict__ H, int n,
                                              int rowsPerBlock) {
  __shared__ float Wl[KDIM * DOUT_T];
  for (int i = threadIdx.x; i < KDIM * DOUT_T; i += 256) Wl[i] = W[i];
  __syncthreads();

  const int col = threadIdx.x % DOUT_T;
  const int sub = threadIdx.x / DOUT_T;  // which row of the concurrent set
  constexpr int RPI = 256 / DOUT_T;      // rows processed per iteration
  const int row0 = blockIdx.x * rowsPerBlock;

  for (int r = sub; r < rowsPerBlock; r += RPI) {
    const int row = row0 + r;
    if (row >= n) break;
    const float4* xr = reinterpret_cast<const float4*>(X + (size_t)row * KDIM);
    float a0 = 0.f, a1 = 0.f, a2 = 0.f, a3 = 0.f;
#pragma unroll
    for (int k4 = 0; k4 < KDIM / 4; ++k4) {
      float4 xv = xr[k4];
      a0 = fmaf(xv.x, Wl[(k4 * 4 + 0) * DOUT_T + col], a0);
      a1 = fmaf(xv.y, Wl[(k4 * 4 + 1) * DOUT_T + col], a1);
      a2 = fmaf(xv.z, Wl[(k4 * 4 + 2) * DOUT_T + col], a2);
      a3 = fmaf(xv.w, Wl[(k4 * 4 + 3) * DOUT_T + col], a3);
    }
    H[(size_t)row * DOUT_T + col] = (a0 + a1) + (a2 + a3);
  }
}

// One wave per node: OUT[i] = sum_{e: dst=i} H[src[e]] * dis[src]*dis[i]
//                           + H[i]*dis[i]^2 + bias   (optional relu)
template <int D, bool RELU>
__global__ __launch_bounds__(256) void k_agg(const float* __restrict__ H,
                                             const int* __restrict__ row_start,
                                             const int* __restrict__ colA,
                                             const float* __restrict__ dis,
                                             const float* __restrict__ bias,
                                             float* __restrict__ OUT, int n) {
  const int wave = threadIdx.x >> 6;
  const int lane = threadIdx.x & 63;
  const int node = blockIdx.x * 4 + wave;
  if (node >= n) return;
  constexpr int C = D / 64;
  float acc[C];
#pragma unroll
  for (int c = 0; c < C; ++c) acc[c] = 0.f;

  const int beg = row_start[node];
  const int end = row_start[node + 1];
  const float di = dis[node];
  for (int e = beg; e < end; ++e) {
    const int s = colA[e];
    const float nrm = dis[s] * di;
    const float* hs = H + (size_t)s * D;
#pragma unroll
    for (int c = 0; c < C; ++c) acc[c] = fmaf(hs[lane + 64 * c], nrm, acc[c]);
  }
  const float* hn = H + (size_t)node * D;
  const float di2 = di * di;
  float* o = OUT + (size_t)node * D;
#pragma unroll
  for (int c = 0; c < C; ++c) {
    float v = acc[c] + hn[lane + 64 * c] * di2 + bias[lane + 64 * c];
    if (RELU) v = fmaxf(v, 0.f);
    o[lane + 64 * c] = v;
  }
}

// batch is sorted ascending -> graph g owns contiguous node range.
// One block per graph: binary-search [beg,end), 4 waves stride the rows,
// lane = output dim (64). LDS-reduce, divide by count. Zero atomics.
__global__ __launch_bounds__(256) void k_pool2(const float* __restrict__ F,
                                               const int* __restrict__ batch,
                                               float* __restrict__ out, int n) {
  const int g = blockIdx.x;
  __shared__ int sb[2];
  if (threadIdx.x < 2) {
    int target = g + threadIdx.x;  // lower_bound(batch, target)
    int lo = 0, hi = n;
    while (lo < hi) {
      int mid = (lo + hi) >> 1;
      if (batch[mid] < target) lo = mid + 1; else hi = mid;
    }
    sb[threadIdx.x] = lo;
  }
  __syncthreads();
  const int beg = sb[0], end = sb[1];
  const int wave = threadIdx.x >> 6;
  const int lane = threadIdx.x & 63;
  float acc = 0.f;
  for (int node = beg + wave; node < end; node += 4)
    acc += F[(size_t)node * 64 + lane];
  __shared__ float red[4][64];
  red[wave][lane] = acc;
  __syncthreads();
  if (wave == 0) {
    float v = (red[0][lane] + red[1][lane]) + (red[2][lane] + red[3][lane]);
    out[g * 64 + lane] = v / fmaxf((float)(end - beg), 1.f);
  }
}

extern "C" void kernel_launch(void* const* d_in, const int* in_sizes, int n_in,
                              void* d_out, int out_size, void* d_ws, size_t ws_size,
                              hipStream_t stream) {
  const float* x     = (const float*)d_in[0];
  const int*   ei    = (const int*)d_in[1];
  const int*   batch = (const int*)d_in[2];
  const float* W1 = (const float*)d_in[3];
  const float* b1 = (const float*)d_in[4];
  const float* W2 = (const float*)d_in[5];
  const float* b2 = (const float*)d_in[6];
  const float* W3 = (const float*)d_in[7];
  const float* b3 = (const float*)d_in[8];

  const int n = in_sizes[0] / KDIM;   // 50000
  const int e = in_sizes[1] / 2;      // 800000
  const int* src = ei;
  const int* dst = ei + e;

  // workspace layout (256B-aligned slices)
  char* p = (char*)d_ws;
  size_t off = 0;
  auto carve = [&](size_t bytes) {
    char* r = p + off;
    off = (off + bytes + 255) & ~(size_t)255;
    return r;
  };
  float* bufA      = (float*)carve((size_t)n * KDIM * 4);
  float* bufB      = (float*)carve((size_t)n * KDIM * 4);
  float* dis       = (float*)carve((size_t)n * 4);
  int*   counts    = (int*)carve((size_t)n * 4);
  int*   row_start = (int*)carve((size_t)(n + 1) * 4);
  int*   cursor    = (int*)carve((size_t)n * 4);
  int*   colA      = (int*)carve((size_t)e * 4);
  int*   blockSums = (int*)carve(512 * 4);
  (void)ws_size;

  const int nb1 = (n + 255) / 256;  // 196 (<=256 required for single-block scan2)
  const int GS = 1024;              // grid for grid-stride kernels

  k_init<<<GS, 256, 0, stream>>>(counts, n);
  k_hist<<<GS, 256, 0, stream>>>(src, dst, counts, e, n);
  k_dis<<<nb1, 256, 0, stream>>>(counts, dis, n);
  k_scan_block<<<nb1, 256, 0, stream>>>(counts, row_start, blockSums, n);
  k_scan_offsets<<<1, 256, 0, stream>>>(blockSums, nb1);
  k_scan_add<<<nb1, 256, 0, stream>>>(row_start, blockSums, cursor, n);
  k_scatter<<<GS, 256, 0, stream>>>(src, dst, cursor, colA, e, n);

  const int gemmGrid = (n + 31) / 32;
  const int aggGrid  = (n + 3) / 4;

  // layer 1
  k_gemm<128><<<gemmGrid, 256, 0, stream>>>(x, W1, bufA, n, 32);
  k_agg<128, true><<<aggGrid, 256, 0, stream>>>(bufA, row_start, colA, dis, b1, bufB, n);
  // layer 2
  k_gemm<128><<<gemmGrid, 256, 0, stream>>>(bufB, W2, bufA, n, 32);
  k_agg<128, true><<<aggGrid, 256, 0, stream>>>(bufA, row_start, colA, dis, b2, bufB, n);
  // layer 3
  k_gemm<64><<<gemmGrid, 256, 0, stream>>>(bufB, W3, bufA, n, 32);
  k_agg<64, false><<<aggGrid, 256, 0, stream>>>(bufA, row_start, colA, dis, b3,
                                                (float*)d_out, n);
  // pooling: segmented reduction over sorted batch
  k_pool2<<<NGRAPH, 256, 0, stream>>>((const float*)d_out, batch,
                                      (float*)d_out + (size_t)n * 64, n);
}

// Round 5
// 523.441 us; speedup vs baseline: 2.1129x; 1.4588x over previous
//
#include <hip/hip_runtime.h>

// GCN 3-layer + mean pool, MI355X.
// R1: pool atomics -> segmented reduction (1106 -> 764us).
// R2 post-mortem: k_gemm was 1 LDS-read/FMA, 17% occupancy, 28% VALUBusy
//   -> 12 TF effective. Rewritten: 128x64 tile, BK=32, LDS-staged x^T + W,
//   8x4 register tile -> 0.375 LDS-floats/FMA, ~89% FMA density.
// k_agg: serial dependent-load chain per wave -> 2 waves/node + x2 unroll
//   (4 chains in flight), LDS partial combine.
// R3/R4: broker timeouts, no data — resubmitted unchanged (attribution
// discipline: never stack a second unmeasured change).

constexpr int KDIM = 128;   // inner dim of all three GEMMs
constexpr int NGRAPH = 64;

__global__ void k_init(int* __restrict__ counts, int n) {
  int i = blockIdx.x * blockDim.x + threadIdx.x;
  int stride = gridDim.x * blockDim.x;
  for (int j = i; j < n; j += stride) counts[j] = 0;
}

__global__ void k_hist(const int* __restrict__ src, const int* __restrict__ dst,
                       int* __restrict__ counts, int e, int n) {
  int i = blockIdx.x * blockDim.x + threadIdx.x;
  int stride = gridDim.x * blockDim.x;
  for (int j = i; j < e; j += stride) {
    int s = src[j], d = dst[j];
    if ((unsigned)s < (unsigned)n && (unsigned)d < (unsigned)n)
      atomicAdd(&counts[d], 1);
  }
}

__global__ void k_dis(const int* __restrict__ counts, float* __restrict__ dis, int n) {
  int i = blockIdx.x * blockDim.x + threadIdx.x;
  int stride = gridDim.x * blockDim.x;
  for (int j = i; j < n; j += stride)
    dis[j] = rsqrtf((float)counts[j] + 1.0f);
}

// per-block exclusive scan; blockSums[b] = block total
__global__ void k_scan_block(const int* __restrict__ in, int* __restrict__ outExcl,
                             int* __restrict__ blockSums, int n) {
  __shared__ int s[256];
  int tid = threadIdx.x;
  int i = blockIdx.x * 256 + tid;
  int v = (i < n) ? in[i] : 0;
  int x = v;
  s[tid] = x;
  __syncthreads();
  for (int off = 1; off < 256; off <<= 1) {
    int t = (tid >= off) ? s[tid - off] : 0;
    __syncthreads();
    x += t;
    s[tid] = x;
    __syncthreads();
  }
  if (i < n) outExcl[i] = x - v;
  if (tid == 255) blockSums[blockIdx.x] = x;
}

__global__ void k_scan_offsets(int* __restrict__ bs, int nb) {
  __shared__ int s[256];
  int tid = threadIdx.x;
  int v = (tid < nb) ? bs[tid] : 0;
  int x = v;
  s[tid] = x;
  __syncthreads();
  for (int off = 1; off < 256; off <<= 1) {
    int t = (tid >= off) ? s[tid - off] : 0;
    __syncthreads();
    x += t;
    s[tid] = x;
    __syncthreads();
  }
  if (tid < nb) bs[tid] = x - v;
  if (tid == nb - 1) bs[256] = x;  // total valid edges
}

__global__ void k_scan_add(int* __restrict__ row_start, const int* __restrict__ bs,
                           int* __restrict__ cursor, int n) {
  int i = blockIdx.x * blockDim.x + threadIdx.x;
  int stride = gridDim.x * blockDim.x;
  for (int j = i; j < n; j += stride) {
    int r = row_start[j] + bs[j >> 8];
    row_start[j] = r;
    cursor[j] = r;
  }
  if (i == 0) row_start[n] = bs[256];
}

__global__ void k_scatter(const int* __restrict__ src, const int* __restrict__ dst,
                          int* __restrict__ cursor, int* __restrict__ colA,
                          int e, int n) {
  int i = blockIdx.x * blockDim.x + threadIdx.x;
  int stride = gridDim.x * blockDim.x;
  for (int j = i; j < e; j += stride) {
    int s = src[j], d = dst[j];
    if ((unsigned)s < (unsigned)n && (unsigned)d < (unsigned)n) {
      int pos = atomicAdd(&cursor[d], 1);
      colA[pos] = s;
    }
  }
}

// H = X @ W.  Block tile 128 rows x 64 cols, BK=32.
// LDS: xT[k][row] (transposed for contiguous fragment reads) + Wl[k][col].
// Thread (tr=tid&15, tc=tid>>4): rows {tr*4..+3, 64+tr*4..+3}, cols tc*4..+3.
// Per k: 3x ds_read_b128 + 32 FMA. Bank analysis: x reads 256B contiguous per
// 16-lane group (2-way, free) + 4x tc broadcast; W reads 4 addrs broadcast.
template <int DOUT>
__global__ __launch_bounds__(256) void k_gemm2(const float* __restrict__ X,
                                               const float* __restrict__ W,
                                               float* __restrict__ H, int n) {
  __shared__ float xT[32][128];  // 16 KB
  __shared__ float Wl[32][64];   // 8 KB
  const int tid = threadIdx.x;
  const int tr = tid & 15;
  const int tc = tid >> 4;
  const int rowBase = blockIdx.x * 128;
  const int colBase = blockIdx.y * 64;

  float acc[8][4];
#pragma unroll
  for (int i = 0; i < 8; ++i)
#pragma unroll
    for (int j = 0; j < 4; ++j) acc[i][j] = 0.f;

  // staging coords (fixed across chunks)
  const int sr = tid >> 1;              // 0..127: which row this thread stages
  const int kh = (tid & 1) * 16;        // which 16-k half
  const int srow = min(rowBase + sr, n - 1);
  const float* xsrc = X + (size_t)srow * KDIM + kh;

  for (int k0 = 0; k0 < KDIM / 32; ++k0) {
    // stage x chunk (transposed)
    {
      const float4* s4 = reinterpret_cast<const float4*>(xsrc + k0 * 32);
      float4 v0 = s4[0], v1 = s4[1], v2 = s4[2], v3 = s4[3];
      xT[kh + 0][sr] = v0.x;  xT[kh + 1][sr] = v0.y;
      xT[kh + 2][sr] = v0.z;  xT[kh + 3][sr] = v0.w;
      xT[kh + 4][sr] = v1.x;  xT[kh + 5][sr] = v1.y;
      xT[kh + 6][sr] = v1.z;  xT[kh + 7][sr] = v1.w;
      xT[kh + 8][sr] = v2.x;  xT[kh + 9][sr] = v2.y;
      xT[kh + 10][sr] = v2.z; xT[kh + 11][sr] = v2.w;
      xT[kh + 12][sr] = v3.x; xT[kh + 13][sr] = v3.y;
      xT[kh + 14][sr] = v3.z; xT[kh + 15][sr] = v3.w;
    }
    // stage W chunk: 32x64 = 512 float4, 2 per thread
#pragma unroll
    for (int q = 0; q < 2; ++q) {
      int f4 = tid + q * 256;
      int k = f4 >> 4;
      int c4 = f4 & 15;
      *reinterpret_cast<float4*>(&Wl[k][c4 * 4]) = *reinterpret_cast<const float4*>(
          W + (size_t)(k0 * 32 + k) * DOUT + colBase + c4 * 4);
    }
    __syncthreads();
#pragma unroll 8
    for (int k = 0; k < 32; ++k) {
      float4 xa = *reinterpret_cast<const float4*>(&xT[k][tr * 4]);
      float4 xb = *reinterpret_cast<const float4*>(&xT[k][64 + tr * 4]);
      float4 wv = *reinterpret_cast<const float4*>(&Wl[k][tc * 4]);
      const float xs[8] = {xa.x, xa.y, xa.z, xa.w, xb.x, xb.y, xb.z, xb.w};
      const float ws[4] = {wv.x, wv.y, wv.z, wv.w};
#pragma unroll
      for (int i = 0; i < 8; ++i)
#pragma unroll
        for (int j = 0; j < 4; ++j) acc[i][j] = fmaf(xs[i], ws[j], acc[i][j]);
    }
    __syncthreads();
  }

#pragma unroll
  for (int i = 0; i < 8; ++i) {
    int row = rowBase + ((i < 4) ? (tr * 4 + i) : (64 + tr * 4 + i - 4));
    if (row < n) {
      float4 o = {acc[i][0], acc[i][1], acc[i][2], acc[i][3]};
      *reinterpret_cast<float4*>(H + (size_t)row * DOUT + colBase + tc * 4) = o;
    }
  }
}

// 2 waves per node (edges split even/odd) + x2 unroll inside each wave:
// 4 independent gather chains in flight. LDS partial combine.
template <int D, bool RELU>
__global__ __launch_bounds__(256) void k_agg2(const float* __restrict__ H,
                                              const int* __restrict__ row_start,
                                              const int* __restrict__ colA,
                                              const float* __restrict__ dis,
                                              const float* __restrict__ bias,
                                              float* __restrict__ OUT, int n) {
  const int wave = threadIdx.x >> 6;
  const int lane = threadIdx.x & 63;
  const int slot = wave >> 1;
  const int half = wave & 1;
  const int node = blockIdx.x * 2 + slot;
  constexpr int C = D / 64;
  __shared__ float red[4][D];

  if (node < n) {
    const int beg = row_start[node];
    const int end = row_start[node + 1];
    const float di = dis[node];
    float accA[C], accB[C];
#pragma unroll
    for (int c = 0; c < C; ++c) { accA[c] = 0.f; accB[c] = 0.f; }
    int e = beg + half;
    for (; e + 2 < end; e += 4) {
      const int s0 = colA[e], s1 = colA[e + 2];
      const float n0 = dis[s0] * di, n1 = dis[s1] * di;
      const float* h0 = H + (size_t)s0 * D;
      const float* h1 = H + (size_t)s1 * D;
#pragma unroll
      for (int c = 0; c < C; ++c) {
        accA[c] = fmaf(h0[lane + 64 * c], n0, accA[c]);
        accB[c] = fmaf(h1[lane + 64 * c], n1, accB[c]);
      }
    }
    for (; e < end; e += 2) {
      const int s0 = colA[e];
      const float n0 = dis[s0] * di;
      const float* h0 = H + (size_t)s0 * D;
#pragma unroll
      for (int c = 0; c < C; ++c) accA[c] = fmaf(h0[lane + 64 * c], n0, accA[c]);
    }
#pragma unroll
    for (int c = 0; c < C; ++c) red[wave][lane + 64 * c] = accA[c] + accB[c];
  } else {
#pragma unroll
    for (int c = 0; c < C; ++c) red[wave][lane + 64 * c] = 0.f;
  }
  __syncthreads();
  if (half == 0 && node < n) {
    const float di = dis[node];
    const float di2 = di * di;
    const float* hn = H + (size_t)node * D;
    float* o = OUT + (size_t)node * D;
#pragma unroll
    for (int c = 0; c < C; ++c) {
      float v = red[wave][lane + 64 * c] + red[wave + 1][lane + 64 * c] +
                hn[lane + 64 * c] * di2 + bias[lane + 64 * c];
      if (RELU) v = fmaxf(v, 0.f);
      o[lane + 64 * c] = v;
    }
  }
}

// batch sorted -> one block per graph, binary-search range, no atomics.
__global__ __launch_bounds__(256) void k_pool2(const float* __restrict__ F,
                                               const int* __restrict__ batch,
                                               float* __restrict__ out, int n) {
  const int g = blockIdx.x;
  __shared__ int sb[2];
  if (threadIdx.x < 2) {
    int target = g + threadIdx.x;
    int lo = 0, hi = n;
    while (lo < hi) {
      int mid = (lo + hi) >> 1;
      if (batch[mid] < target) lo = mid + 1; else hi = mid;
    }
    sb[threadIdx.x] = lo;
  }
  __syncthreads();
  const int beg = sb[0], end = sb[1];
  const int wave = threadIdx.x >> 6;
  const int lane = threadIdx.x & 63;
  float acc = 0.f;
  for (int node = beg + wave; node < end; node += 4)
    acc += F[(size_t)node * 64 + lane];
  __shared__ float red[4][64];
  red[wave][lane] = acc;
  __syncthreads();
  if (wave == 0) {
    float v = (red[0][lane] + red[1][lane]) + (red[2][lane] + red[3][lane]);
    out[g * 64 + lane] = v / fmaxf((float)(end - beg), 1.f);
  }
}

extern "C" void kernel_launch(void* const* d_in, const int* in_sizes, int n_in,
                              void* d_out, int out_size, void* d_ws, size_t ws_size,
                              hipStream_t stream) {
  const float* x     = (const float*)d_in[0];
  const int*   ei    = (const int*)d_in[1];
  const int*   batch = (const int*)d_in[2];
  const float* W1 = (const float*)d_in[3];
  const float* b1 = (const float*)d_in[4];
  const float* W2 = (const float*)d_in[5];
  const float* b2 = (const float*)d_in[6];
  const float* W3 = (const float*)d_in[7];
  const float* b3 = (const float*)d_in[8];

  const int n = in_sizes[0] / KDIM;   // 50000
  const int e = in_sizes[1] / 2;      // 800000
  const int* src = ei;
  const int* dst = ei + e;

  char* p = (char*)d_ws;
  size_t off = 0;
  auto carve = [&](size_t bytes) {
    char* r = p + off;
    off = (off + bytes + 255) & ~(size_t)255;
    return r;
  };
  float* bufA      = (float*)carve((size_t)n * KDIM * 4);
  float* bufB      = (float*)carve((size_t)n * KDIM * 4);
  float* dis       = (float*)carve((size_t)n * 4);
  int*   counts    = (int*)carve((size_t)n * 4);
  int*   row_start = (int*)carve((size_t)(n + 1) * 4);
  int*   cursor    = (int*)carve((size_t)n * 4);
  int*   colA      = (int*)carve((size_t)e * 4);
  int*   blockSums = (int*)carve(512 * 4);
  (void)ws_size;

  const int nb1 = (n + 255) / 256;
  const int GS = 1024;

  k_init<<<GS, 256, 0, stream>>>(counts, n);
  k_hist<<<GS, 256, 0, stream>>>(src, dst, counts, e, n);
  k_dis<<<nb1, 256, 0, stream>>>(counts, dis, n);
  k_scan_block<<<nb1, 256, 0, stream>>>(counts, row_start, blockSums, n);
  k_scan_offsets<<<1, 256, 0, stream>>>(blockSums, nb1);
  k_scan_add<<<nb1, 256, 0, stream>>>(row_start, blockSums, cursor, n);
  k_scatter<<<GS, 256, 0, stream>>>(src, dst, cursor, colA, e, n);

  const int rowBlocks = (n + 127) / 128;  // 391
  const int aggGrid = (n + 1) / 2;        // 2 nodes per block

  // layer 1
  k_gemm2<128><<<dim3(rowBlocks, 2), 256, 0, stream>>>(x, W1, bufA, n);
  k_agg2<128, true><<<aggGrid, 256, 0, stream>>>(bufA, row_start, colA, dis, b1, bufB, n);
  // layer 2
  k_gemm2<128><<<dim3(rowBlocks, 2), 256, 0, stream>>>(bufB, W2, bufA, n);
  k_agg2<128, true><<<aggGrid, 256, 0, stream>>>(bufA, row_start, colA, dis, b2, bufB, n);
  // layer 3
  k_gemm2<64><<<dim3(rowBlocks, 1), 256, 0, stream>>>(bufB, W3, bufA, n);
  k_agg2<64, false><<<aggGrid, 256, 0, stream>>>(bufA, row_start, colA, dis, b3,
                                                 (float*)d_out, n);
  // pooling
  k_pool2<<<NGRAPH, 256, 0, stream>>>((const float*)d_out, batch,
                                      (float*)d_out + (size_t)n * 64, n);
}

// Round 6
// 495.470 us; speedup vs baseline: 2.2322x; 1.0565x over previous
//
#include <hip/hip_runtime.h>

// GCN 3-layer + mean pool, MI355X.
// R1: pool atomics -> segmented reduction (1106 -> 764us).
// R2: k_gemm rewrite 128x64 tile (confirmed R5: gemm left top-5).
// R5 post-mortem: k_agg2 71us, VGPR=12 (!), VALUBusy 24%, HBM 17%, occ 74%
//   -> latency-bound; compiler serialized the gather chains under 12 VGPRs.
// R6: k_agg3 — lane covers C consecutive dims (float2 load = whole row in
//   one instr), explicit 4-chain unroll with grouped loads -> >=4 gathers
//   in flight per wave. Predict 71 -> ~30us, VGPR -> ~40-60.

constexpr int KDIM = 128;   // inner dim of all three GEMMs
constexpr int NGRAPH = 64;

__global__ void k_init(int* __restrict__ counts, int n) {
  int i = blockIdx.x * blockDim.x + threadIdx.x;
  int stride = gridDim.x * blockDim.x;
  for (int j = i; j < n; j += stride) counts[j] = 0;
}

__global__ void k_hist(const int* __restrict__ src, const int* __restrict__ dst,
                       int* __restrict__ counts, int e, int n) {
  int i = blockIdx.x * blockDim.x + threadIdx.x;
  int stride = gridDim.x * blockDim.x;
  for (int j = i; j < e; j += stride) {
    int s = src[j], d = dst[j];
    if ((unsigned)s < (unsigned)n && (unsigned)d < (unsigned)n)
      atomicAdd(&counts[d], 1);
  }
}

__global__ void k_dis(const int* __restrict__ counts, float* __restrict__ dis, int n) {
  int i = blockIdx.x * blockDim.x + threadIdx.x;
  int stride = gridDim.x * blockDim.x;
  for (int j = i; j < n; j += stride)
    dis[j] = rsqrtf((float)counts[j] + 1.0f);
}

// per-block exclusive scan; blockSums[b] = block total
__global__ void k_scan_block(const int* __restrict__ in, int* __restrict__ outExcl,
                             int* __restrict__ blockSums, int n) {
  __shared__ int s[256];
  int tid = threadIdx.x;
  int i = blockIdx.x * 256 + tid;
  int v = (i < n) ? in[i] : 0;
  int x = v;
  s[tid] = x;
  __syncthreads();
  for (int off = 1; off < 256; off <<= 1) {
    int t = (tid >= off) ? s[tid - off] : 0;
    __syncthreads();
    x += t;
    s[tid] = x;
    __syncthreads();
  }
  if (i < n) outExcl[i] = x - v;
  if (tid == 255) blockSums[blockIdx.x] = x;
}

__global__ void k_scan_offsets(int* __restrict__ bs, int nb) {
  __shared__ int s[256];
  int tid = threadIdx.x;
  int v = (tid < nb) ? bs[tid] : 0;
  int x = v;
  s[tid] = x;
  __syncthreads();
  for (int off = 1; off < 256; off <<= 1) {
    int t = (tid >= off) ? s[tid - off] : 0;
    __syncthreads();
    x += t;
    s[tid] = x;
    __syncthreads();
  }
  if (tid < nb) bs[tid] = x - v;
  if (tid == nb - 1) bs[256] = x;  // total valid edges
}

__global__ void k_scan_add(int* __restrict__ row_start, const int* __restrict__ bs,
                           int* __restrict__ cursor, int n) {
  int i = blockIdx.x * blockDim.x + threadIdx.x;
  int stride = gridDim.x * blockDim.x;
  for (int j = i; j < n; j += stride) {
    int r = row_start[j] + bs[j >> 8];
    row_start[j] = r;
    cursor[j] = r;
  }
  if (i == 0) row_start[n] = bs[256];
}

__global__ void k_scatter(const int* __restrict__ src, const int* __restrict__ dst,
                          int* __restrict__ cursor, int* __restrict__ colA,
                          int e, int n) {
  int i = blockIdx.x * blockDim.x + threadIdx.x;
  int stride = gridDim.x * blockDim.x;
  for (int j = i; j < e; j += stride) {
    int s = src[j], d = dst[j];
    if ((unsigned)s < (unsigned)n && (unsigned)d < (unsigned)n) {
      int pos = atomicAdd(&cursor[d], 1);
      colA[pos] = s;
    }
  }
}

// H = X @ W.  Block tile 128 rows x 64 cols, BK=32. (unchanged from R2)
template <int DOUT>
__global__ __launch_bounds__(256) void k_gemm2(const float* __restrict__ X,
                                               const float* __restrict__ W,
                                               float* __restrict__ H, int n) {
  __shared__ float xT[32][128];  // 16 KB
  __shared__ float Wl[32][64];   // 8 KB
  const int tid = threadIdx.x;
  const int tr = tid & 15;
  const int tc = tid >> 4;
  const int rowBase = blockIdx.x * 128;
  const int colBase = blockIdx.y * 64;

  float acc[8][4];
#pragma unroll
  for (int i = 0; i < 8; ++i)
#pragma unroll
    for (int j = 0; j < 4; ++j) acc[i][j] = 0.f;

  const int sr = tid >> 1;
  const int kh = (tid & 1) * 16;
  const int srow = min(rowBase + sr, n - 1);
  const float* xsrc = X + (size_t)srow * KDIM + kh;

  for (int k0 = 0; k0 < KDIM / 32; ++k0) {
    {
      const float4* s4 = reinterpret_cast<const float4*>(xsrc + k0 * 32);
      float4 v0 = s4[0], v1 = s4[1], v2 = s4[2], v3 = s4[3];
      xT[kh + 0][sr] = v0.x;  xT[kh + 1][sr] = v0.y;
      xT[kh + 2][sr] = v0.z;  xT[kh + 3][sr] = v0.w;
      xT[kh + 4][sr] = v1.x;  xT[kh + 5][sr] = v1.y;
      xT[kh + 6][sr] = v1.z;  xT[kh + 7][sr] = v1.w;
      xT[kh + 8][sr] = v2.x;  xT[kh + 9][sr] = v2.y;
      xT[kh + 10][sr] = v2.z; xT[kh + 11][sr] = v2.w;
      xT[kh + 12][sr] = v3.x; xT[kh + 13][sr] = v3.y;
      xT[kh + 14][sr] = v3.z; xT[kh + 15][sr] = v3.w;
    }
#pragma unroll
    for (int q = 0; q < 2; ++q) {
      int f4 = tid + q * 256;
      int k = f4 >> 4;
      int c4 = f4 & 15;
      *reinterpret_cast<float4*>(&Wl[k][c4 * 4]) = *reinterpret_cast<const float4*>(
          W + (size_t)(k0 * 32 + k) * DOUT + colBase + c4 * 4);
    }
    __syncthreads();
#pragma unroll 8
    for (int k = 0; k < 32; ++k) {
      float4 xa = *reinterpret_cast<const float4*>(&xT[k][tr * 4]);
      float4 xb = *reinterpret_cast<const float4*>(&xT[k][64 + tr * 4]);
      float4 wv = *reinterpret_cast<const float4*>(&Wl[k][tc * 4]);
      const float xs[8] = {xa.x, xa.y, xa.z, xa.w, xb.x, xb.y, xb.z, xb.w};
      const float ws[4] = {wv.x, wv.y, wv.z, wv.w};
#pragma unroll
      for (int i = 0; i < 8; ++i)
#pragma unroll
        for (int j = 0; j < 4; ++j) acc[i][j] = fmaf(xs[i], ws[j], acc[i][j]);
    }
    __syncthreads();
  }

#pragma unroll
  for (int i = 0; i < 8; ++i) {
    int row = rowBase + ((i < 4) ? (tr * 4 + i) : (64 + tr * 4 + i - 4));
    if (row < n) {
      float4 o = {acc[i][0], acc[i][1], acc[i][2], acc[i][3]};
      *reinterpret_cast<float4*>(H + (size_t)row * DOUT + colBase + tc * 4) = o;
    }
  }
}

// R6 aggregation: 2 waves/node (even/odd edges), lane covers C=D/64
// CONSECUTIVE dims -> one float2 (D=128) / float (D=64) load grabs the
// lane's slice of a row; 4 explicit chains with grouped loads for MLP.
template <int D, bool RELU>
__global__ __launch_bounds__(256) void k_agg3(const float* __restrict__ H,
                                              const int* __restrict__ row_start,
                                              const int* __restrict__ colA,
                                              const float* __restrict__ dis,
                                              const float* __restrict__ bias,
                                              float* __restrict__ OUT, int n) {
  const int wave = threadIdx.x >> 6;
  const int lane = threadIdx.x & 63;
  const int slot = wave >> 1;
  const int half = wave & 1;
  const int node = blockIdx.x * 2 + slot;
  constexpr int C = D / 64;  // 2 (D=128) or 1 (D=64)
  __shared__ float red[4][D];

  if (node < n) {
    const int beg = row_start[node];
    const int end = row_start[node + 1];
    const float di = dis[node];
    float a0[C], a1[C], a2[C], a3[C];
#pragma unroll
    for (int c = 0; c < C; ++c) { a0[c] = 0.f; a1[c] = 0.f; a2[c] = 0.f; a3[c] = 0.f; }

    int e = beg + half;
    // main loop: 4 independent gather chains in flight
    for (; e + 6 < end; e += 8) {
      const int s0 = colA[e], s1 = colA[e + 2], s2 = colA[e + 4], s3 = colA[e + 6];
      const float w0 = dis[s0], w1 = dis[s1], w2 = dis[s2], w3 = dis[s3];
      const float* p0 = H + (size_t)s0 * D + C * lane;
      const float* p1 = H + (size_t)s1 * D + C * lane;
      const float* p2 = H + (size_t)s2 * D + C * lane;
      const float* p3 = H + (size_t)s3 * D + C * lane;
      if constexpr (C == 2) {
        const float2 h0 = *reinterpret_cast<const float2*>(p0);
        const float2 h1 = *reinterpret_cast<const float2*>(p1);
        const float2 h2 = *reinterpret_cast<const float2*>(p2);
        const float2 h3 = *reinterpret_cast<const float2*>(p3);
        a0[0] = fmaf(h0.x, w0 * di, a0[0]); a0[1] = fmaf(h0.y, w0 * di, a0[1]);
        a1[0] = fmaf(h1.x, w1 * di, a1[0]); a1[1] = fmaf(h1.y, w1 * di, a1[1]);
        a2[0] = fmaf(h2.x, w2 * di, a2[0]); a2[1] = fmaf(h2.y, w2 * di, a2[1]);
        a3[0] = fmaf(h3.x, w3 * di, a3[0]); a3[1] = fmaf(h3.y, w3 * di, a3[1]);
      } else {
        a0[0] = fmaf(*p0, w0 * di, a0[0]);
        a1[0] = fmaf(*p1, w1 * di, a1[0]);
        a2[0] = fmaf(*p2, w2 * di, a2[0]);
        a3[0] = fmaf(*p3, w3 * di, a3[0]);
      }
    }
    // remainder
    for (; e < end; e += 2) {
      const int s0 = colA[e];
      const float w0 = dis[s0];
      const float* p0 = H + (size_t)s0 * D + C * lane;
#pragma unroll
      for (int c = 0; c < C; ++c) a0[c] = fmaf(p0[c], w0 * di, a0[c]);
    }
#pragma unroll
    for (int c = 0; c < C; ++c)
      red[wave][C * lane + c] = (a0[c] + a1[c]) + (a2[c] + a3[c]);
  } else {
#pragma unroll
    for (int c = 0; c < C; ++c) red[wave][C * lane + c] = 0.f;
  }
  __syncthreads();
  if (half == 0 && node < n) {
    const float di = dis[node];
    const float di2 = di * di;
    const float* hn = H + (size_t)node * D + C * lane;
    const float* bi = bias + C * lane;
    float* o = OUT + (size_t)node * D + C * lane;
#pragma unroll
    for (int c = 0; c < C; ++c) {
      float v = red[wave][C * lane + c] + red[wave + 1][C * lane + c] +
                hn[c] * di2 + bi[c];
      if (RELU) v = fmaxf(v, 0.f);
      o[c] = v;
    }
  }
}

// batch sorted -> one block per graph, binary-search range, no atomics.
__global__ __launch_bounds__(256) void k_pool2(const float* __restrict__ F,
                                               const int* __restrict__ batch,
                                               float* __restrict__ out, int n) {
  const int g = blockIdx.x;
  __shared__ int sb[2];
  if (threadIdx.x < 2) {
    int target = g + threadIdx.x;
    int lo = 0, hi = n;
    while (lo < hi) {
      int mid = (lo + hi) >> 1;
      if (batch[mid] < target) lo = mid + 1; else hi = mid;
    }
    sb[threadIdx.x] = lo;
  }
  __syncthreads();
  const int beg = sb[0], end = sb[1];
  const int wave = threadIdx.x >> 6;
  const int lane = threadIdx.x & 63;
  float acc = 0.f;
  for (int node = beg + wave; node < end; node += 4)
    acc += F[(size_t)node * 64 + lane];
  __shared__ float red[4][64];
  red[wave][lane] = acc;
  __syncthreads();
  if (wave == 0) {
    float v = (red[0][lane] + red[1][lane]) + (red[2][lane] + red[3][lane]);
    out[g * 64 + lane] = v / fmaxf((float)(end - beg), 1.f);
  }
}

extern "C" void kernel_launch(void* const* d_in, const int* in_sizes, int n_in,
                              void* d_out, int out_size, void* d_ws, size_t ws_size,
                              hipStream_t stream) {
  const float* x     = (const float*)d_in[0];
  const int*   ei    = (const int*)d_in[1];
  const int*   batch = (const int*)d_in[2];
  const float* W1 = (const float*)d_in[3];
  const float* b1 = (const float*)d_in[4];
  const float* W2 = (const float*)d_in[5];
  const float* b2 = (const float*)d_in[6];
  const float* W3 = (const float*)d_in[7];
  const float* b3 = (const float*)d_in[8];

  const int n = in_sizes[0] / KDIM;   // 50000
  const int e = in_sizes[1] / 2;      // 800000
  const int* src = ei;
  const int* dst = ei + e;

  char* p = (char*)d_ws;
  size_t off = 0;
  auto carve = [&](size_t bytes) {
    char* r = p + off;
    off = (off + bytes + 255) & ~(size_t)255;
    return r;
  };
  float* bufA      = (float*)carve((size_t)n * KDIM * 4);
  float* bufB      = (float*)carve((size_t)n * KDIM * 4);
  float* dis       = (float*)carve((size_t)n * 4);
  int*   counts    = (int*)carve((size_t)n * 4);
  int*   row_start = (int*)carve((size_t)(n + 1) * 4);
  int*   cursor    = (int*)carve((size_t)n * 4);
  int*   colA      = (int*)carve((size_t)e * 4);
  int*   blockSums = (int*)carve(512 * 4);
  (void)ws_size;

  const int nb1 = (n + 255) / 256;
  const int GS = 1024;

  k_init<<<GS, 256, 0, stream>>>(counts, n);
  k_hist<<<GS, 256, 0, stream>>>(src, dst, counts, e, n);
  k_dis<<<nb1, 256, 0, stream>>>(counts, dis, n);
  k_scan_block<<<nb1, 256, 0, stream>>>(counts, row_start, blockSums, n);
  k_scan_offsets<<<1, 256, 0, stream>>>(blockSums, nb1);
  k_scan_add<<<nb1, 256, 0, stream>>>(row_start, blockSums, cursor, n);
  k_scatter<<<GS, 256, 0, stream>>>(src, dst, cursor, colA, e, n);

  const int rowBlocks = (n + 127) / 128;  // 391
  const int aggGrid = (n + 1) / 2;        // 2 nodes per block

  // layer 1
  k_gemm2<128><<<dim3(rowBlocks, 2), 256, 0, stream>>>(x, W1, bufA, n);
  k_agg3<128, true><<<aggGrid, 256, 0, stream>>>(bufA, row_start, colA, dis, b1, bufB, n);
  // layer 2
  k_gemm2<128><<<dim3(rowBlocks, 2), 256, 0, stream>>>(bufB, W2, bufA, n);
  k_agg3<128, true><<<aggGrid, 256, 0, stream>>>(bufA, row_start, colA, dis, b2, bufB, n);
  // layer 3
  k_gemm2<64><<<dim3(rowBlocks, 1), 256, 0, stream>>>(bufB, W3, bufA, n);
  k_agg3<64, false><<<aggGrid, 256, 0, stream>>>(bufA, row_start, colA, dis, b3,
                                                 (float*)d_out, n);
  // pooling
  k_pool2<<<NGRAPH, 256, 0, stream>>>((const float*)d_out, batch,
                                      (float*)d_out + (size_t)n * 64, n);
}